// Round 4
// baseline (334.115 us; speedup 1.0000x reference)
//
#include <hip/hip_runtime.h>

#define NB 147456   // C*C*KH*KW per sample
#define NB2 73728
#define ZD 256
#define BSZ 32
#define CCH 128

typedef __attribute__((ext_vector_type(8))) short short8;
typedef __attribute__((ext_vector_type(16))) float floatx16;

__device__ __forceinline__ unsigned short f2bf(float f) {
    unsigned int u = __float_as_uint(f);
    return (unsigned short)((u + 0x7fffu + ((u >> 16) & 1u)) >> 16);
}

// ---- K1: h = relu(z@W+b); BN over batch; affine; -> bf16 Wk natural [b][n] --------------------
// 2 cols/thread; unroll-2 double-buffered 16-deep prefetch (no register copies, no vmcnt(0) drain
// of the next chunk at the consume point of the current one).
__global__ __launch_bounds__(128) void hyper_gemm_bn(
    const float* __restrict__ z, const float* __restrict__ dw,
    const float* __restrict__ db, const float* __restrict__ gamma,
    const float* __restrict__ beta, unsigned short* __restrict__ wkn)
{
    __shared__ float zs[ZD * BSZ];            // natural [b][k]; reads are wave-broadcast b128
    int t = threadIdx.x;
    {
        const float4* z4 = (const float4*)z;
        float4* zw = (float4*)zs;
#pragma unroll
        for (int i = 0; i < 16; i++) zw[t + i * 128] = z4[t + i * 128];
    }
    __syncthreads();

    int n0 = (blockIdx.x * 128 + t) * 2;      // 576 blocks
    size_t nc = (size_t)(n0 >> 1);
    const float2* dw2 = (const float2*)dw;

    float acc0[32], acc1[32];
#pragma unroll
    for (int b = 0; b < 32; b++) { acc0[b] = 0.f; acc1[b] = 0.f; }

    const float4* zs4 = (const float4*)zs;
    float2 wa[16], wb[16];
#pragma unroll
    for (int j = 0; j < 16; j++) wa[j] = dw2[(size_t)j * NB2 + nc];

#define FMA_CHUNK(CC, WBUF)                                              \
    {                                                                    \
        _Pragma("unroll")                                                \
        for (int b = 0; b < 32; b++) {                                   \
            float4 z0 = zs4[b * 64 + (CC) * 4 + 0];                      \
            float4 z1 = zs4[b * 64 + (CC) * 4 + 1];                      \
            float4 z2 = zs4[b * 64 + (CC) * 4 + 2];                      \
            float4 z3 = zs4[b * 64 + (CC) * 4 + 3];                      \
            float zv[16] = { z0.x, z0.y, z0.z, z0.w, z1.x, z1.y, z1.z,   \
                             z1.w, z2.x, z2.y, z2.z, z2.w, z3.x, z3.y,   \
                             z3.z, z3.w };                               \
            _Pragma("unroll")                                            \
            for (int j = 0; j < 16; j++) {                               \
                acc0[b] += zv[j] * WBUF[j].x;                            \
                acc1[b] += zv[j] * WBUF[j].y;                            \
            }                                                            \
        }                                                                \
    }

    for (int c = 0; c < 16; c += 2) {
#pragma unroll
        for (int j = 0; j < 16; j++)
            wb[j] = dw2[(size_t)((c + 1) * 16 + j) * NB2 + nc];
        FMA_CHUNK(c, wa)
        if (c + 2 < 16) {
#pragma unroll
            for (int j = 0; j < 16; j++)
                wa[j] = dw2[(size_t)((c + 2) * 16 + j) * NB2 + nc];
        }
        FMA_CHUNK(c + 1, wb)
    }
#undef FMA_CHUNK

    float bias0 = db[n0], bias1 = db[n0 + 1];
    float s0 = 0.f, q0 = 0.f, s1 = 0.f, q1 = 0.f;
#pragma unroll
    for (int b = 0; b < 32; b++) {
        float h0 = fmaxf(acc0[b] + bias0, 0.f); acc0[b] = h0; s0 += h0; q0 += h0 * h0;
        float h1 = fmaxf(acc1[b] + bias1, 0.f); acc1[b] = h1; s1 += h1; q1 += h1 * h1;
    }
    float m0 = s0 * (1.f/32.f), m1 = s1 * (1.f/32.f);
    float v0 = fmaxf(q0 * (1.f/32.f) - m0 * m0, 0.f);
    float v1 = fmaxf(q1 * (1.f/32.f) - m1 * m1, 0.f);
    float sc0 = gamma[n0]     / (sqrtf(v0) + 1e-6f), bt0 = beta[n0];
    float sc1 = gamma[n0 + 1] / (sqrtf(v1) + 1e-6f), bt1 = beta[n0 + 1];

    unsigned int* wout = (unsigned int*)wkn;
#pragma unroll
    for (int b = 0; b < 32; b++) {
        float w0 = sc0 * (acc0[b] - m0) + bt0;
        float w1 = sc1 * (acc1[b] - m1) + bt1;
        wout[((size_t)b * NB + n0) >> 1] = (unsigned int)f2bf(w0) | ((unsigned int)f2bf(w1) << 16);
    }
}

// ---- fused: blocks 0..255 repack wkn->wkt; blocks 256..1279 transpose x -> xT bf16 -----------
__global__ __launch_bounds__(256) void repack_xt(
    const unsigned short* __restrict__ wkn, unsigned short* __restrict__ wkt,
    const float* __restrict__ x, unsigned short* __restrict__ xb16)
{
    __shared__ char lmem[16 * 580 * 4];       // 37120 B, shared by both roles
    int t = threadIdx.x;
    if (blockIdx.x < 256) {
        // repack: wkn[b][s*1152 + f*9 + uv] -> wkt[b][uv][f][s]
        unsigned int* lt = (unsigned int*)lmem;   // [16][580]
        int b = blockIdx.x >> 3;
        int s0 = (blockIdx.x & 7) * 16;
        const unsigned int* src = (const unsigned int*)wkn + ((size_t)b * NB >> 1) + (size_t)s0 * 576;
#pragma unroll
        for (int i = 0; i < 36; i++) {
            int idx = t + i * 256;
            int si = idx / 576;
            int j2 = idx - si * 576;
            lt[si * 580 + j2] = src[(size_t)si * 576 + j2];
        }
        __syncthreads();
        const unsigned short* ls = (const unsigned short*)lt;
#pragma unroll
        for (int i = 0; i < 9; i++) {
            int tau = t + i * 256;
            int half = tau & 1;
            int unit = tau >> 1;
            int uv = unit >> 7;
            int f = unit & 127;
            int col = f * 9 + uv;
            unsigned short v[8];
#pragma unroll
            for (int ss = 0; ss < 8; ss++)
                v[ss] = ls[(half * 8 + ss) * 1160 + col];
            uint4 o;
            o.x = v[0] | ((unsigned)v[1] << 16);
            o.y = v[2] | ((unsigned)v[3] << 16);
            o.z = v[4] | ((unsigned)v[5] << 16);
            o.w = v[6] | ((unsigned)v[7] << 16);
            ((uint4*)wkt)[((((size_t)b * 9 + uv) * 128 + f) * 16) + (s0 >> 3) + half] = o;
        }
    } else {
        // x transpose: x[b][s][p][q] fp32 -> xT[b][p][q][s] bf16
        unsigned short* lx = (unsigned short*)lmem;   // [32][130]
        int idx = blockIdx.x - 256;
        int p = idx & 31;
        int b = idx >> 5;
        const float* xp = x + (size_t)b * CCH * 1024 + p * 32;
#pragma unroll
        for (int i = 0; i < 16; i++) {
            int ii = t + i * 256;
            int s = ii >> 5;
            int q = ii & 31;
            lx[q * 130 + s] = f2bf(xp[(size_t)s * 1024 + q]);
        }
        __syncthreads();
#pragma unroll
        for (int i = 0; i < 2; i++) {
            int tau = t + i * 256;
            int q = tau >> 4;
            int ch = tau & 15;
            const unsigned short* r = &lx[q * 130 + ch * 8];
            uint4 o;
            o.x = r[0] | ((unsigned)r[1] << 16);
            o.y = r[2] | ((unsigned)r[3] << 16);
            o.z = r[4] | ((unsigned)r[5] << 16);
            o.w = r[6] | ((unsigned)r[7] << 16);
            ((uint4*)xb16)[((((size_t)b * 32 + p) * 32) + q) * 16 + ch] = o;
        }
    }
}

// ---- conv: out[b,f,p,q] = sum_uv sum_s Wuv[f,s]*x[b,s,p+u-1,q+v-1] + cb[f] + x[b,f,p,q] -------
// Block: 2 waves = 128f x 2 rows. XCD-swizzled so each XCD serves 4 samples (A stays L2-resident).
__global__ __launch_bounds__(128) void conv_mfma(
    const float* __restrict__ x, const unsigned short* __restrict__ xb16,
    const unsigned short* __restrict__ wkt, const float* __restrict__ cb,
    float* __restrict__ out)
{
    __shared__ short8 lds8[4 * 34 * 17];      // [row][col][s-chunk], col stride 17 short8
    int t = threadIdx.x;
    int w = blockIdx.x;                       // 512 blocks
    int xcd = w & 7;
    int slot = w >> 3;
    int b = (xcd << 2) | (slot >> 4);         // wg->XCD is w%8 round-robin: XCD x owns b in [4x,4x+4)
    int p0 = (slot & 15) * 2;
    int lane = t & 63;
    int fbase = (t >> 6) * 64;
    int qcol = lane & 31;
    int klane = lane >> 5;

    {   // zero halo columns 0 and 33
        int r = t >> 5;
        int col = ((t >> 4) & 1) ? 33 : 0;
        int ch = t & 15;
        short8 zz = { 0, 0, 0, 0, 0, 0, 0, 0 };
        lds8[(r * 34 + col) * 17 + ch] = zz;
    }
    const uint4* xsrc = (const uint4*)xb16;
#pragma unroll
    for (int i = 0; i < 16; i++) {
        int tau = t + i * 128;                // 2048 uint4: rows p0-1..p0+2, cols 0..31, ch 0..15
        int ch = tau & 15;
        int q = (tau >> 4) & 31;
        int r = tau >> 9;
        int prow = p0 - 1 + r;
        uint4 v = make_uint4(0, 0, 0, 0);
        if (prow >= 0 && prow < 32)
            v = xsrc[((((size_t)b * 32 + prow) * 32) + q) * 16 + ch];
        *(uint4*)&lds8[(r * 34 + q + 1) * 17 + ch] = v;
    }
    __syncthreads();

    floatx16 acc[2][2];
#pragma unroll
    for (int mi = 0; mi < 2; mi++)
#pragma unroll
        for (int ni = 0; ni < 2; ni++)
#pragma unroll
            for (int r = 0; r < 16; r++) acc[mi][ni][r] = 0.f;

    const short8* A8 = (const short8*)wkt + ((size_t)b * 9 << 11);
#pragma unroll
    for (int v = 0; v < 3; v++)
#pragma unroll
    for (int ks = 0; ks < 8; ks++) {
        int koff = ks * 2 + klane;
        short8 br[4];
#pragma unroll
        for (int r = 0; r < 4; r++)           // B rows shared across u (u and u+1 overlap)
            br[r] = lds8[(r * 34 + qcol + v) * 17 + koff];
#pragma unroll
        for (int u = 0; u < 3; u++) {
            const short8* Au = A8 + ((size_t)(u * 3 + v) << 11);
            short8 a0 = Au[(fbase + qcol) * 16 + koff];
            short8 a1 = Au[(fbase + 32 + qcol) * 16 + koff];
            acc[0][0] = __builtin_amdgcn_mfma_f32_32x32x16_bf16(a0, br[u],     acc[0][0], 0, 0, 0);
            acc[0][1] = __builtin_amdgcn_mfma_f32_32x32x16_bf16(a0, br[u + 1], acc[0][1], 0, 0, 0);
            acc[1][0] = __builtin_amdgcn_mfma_f32_32x32x16_bf16(a1, br[u],     acc[1][0], 0, 0, 0);
            acc[1][1] = __builtin_amdgcn_mfma_f32_32x32x16_bf16(a1, br[u + 1], acc[1][1], 0, 0, 0);
        }
    }

    const size_t xb = (size_t)b * CCH * 1024;
#pragma unroll
    for (int mi = 0; mi < 2; mi++)
#pragma unroll
    for (int ni = 0; ni < 2; ni++) {
        int p = p0 + ni;
#pragma unroll
        for (int r = 0; r < 16; r++) {
            int fl = (r & 3) + 8 * (r >> 2) + 4 * klane;
            int f = fbase + mi * 32 + fl;
            size_t idx = xb + (size_t)f * 1024 + p * 32 + qcol;
            out[idx] = acc[mi][ni][r] + x[idx] + cb[f];
        }
    }
}

extern "C" void kernel_launch(void* const* d_in, const int* in_sizes, int n_in,
                              void* d_out, int out_size, void* d_ws, size_t ws_size,
                              hipStream_t stream) {
    const float* x     = (const float*)d_in[0];
    const float* z     = (const float*)d_in[1];
    const float* dw    = (const float*)d_in[2];
    const float* db    = (const float*)d_in[3];
    const float* gamma = (const float*)d_in[4];
    const float* beta  = (const float*)d_in[5];
    const float* cb    = (const float*)d_in[6];
    float* out = (float*)d_out;

    unsigned short* wkn  = (unsigned short*)d_ws;                                       // 9.44 MB
    unsigned short* wkt  = (unsigned short*)((char*)d_ws + (size_t)BSZ * NB * 2);       // 9.44 MB
    unsigned short* xb16 = (unsigned short*)((char*)d_ws + (size_t)BSZ * NB * 4);       // 8.4 MB

    hyper_gemm_bn<<<NB / 256, 128, 0, stream>>>(z, dw, db, gamma, beta, wkn);
    repack_xt<<<256 + 1024, 256, 0, stream>>>(wkn, wkt, x, xb16);
    conv_mfma<<<512, 128, 0, stream>>>(x, xb16, wkt, cb, out);
}